// Round 1
// 269.183 us; speedup vs baseline: 1.0357x; 1.0357x over previous
//
#include <hip/hip_runtime.h>
#include <stdint.h>

typedef _Float16 f16;
typedef __attribute__((ext_vector_type(8))) _Float16 f16x8;
typedef __attribute__((ext_vector_type(4))) _Float16 f16x4;
typedef __attribute__((ext_vector_type(4))) float f32x4;

#define BK 32

typedef __attribute__((address_space(3))) uint32_t lds_u32;
typedef const __attribute__((address_space(1))) uint32_t glb_u32;

__device__ __forceinline__ void gload_lds16(const void* g, void* l) {
    // async global->LDS, 16B per lane; LDS dest = wave-uniform base + lane*16
    __builtin_amdgcn_global_load_lds((glb_u32*)g, (lds_u32*)l, 16, 0, 0);
}

// C[M,N] = A[M,K] * B[N,K]^T  (both f16 row-major), fp32 accumulate.
// Tile TM x TN; 4 waves; wave-tile (TM/2)x(TN/2).
// Staging: XOR-swizzled, coalescing-preserving (R5: conflicts == 0; R3/R4
// lesson: never permute lanes across rows -> 4x VMEM requests).
// OUT_MODE: 0 = fp32 [M,N] + bias (scaled), bias[gn]
//           1 = f16 out, per-batch stride sCb, bias[bz*N+gn] (per-batch col bias)
//           3 = fused proj (TM=TN=128): gn<1024 -> Qh flat f16 [M,1024];
//               else Vo^T f16 [B][1024][2048] + bias2 (batch = gm>>11)
// CAUSAL: 0 = none; 1 = triangular flat bx (scores);
//         2 = PV: Kend=m0+TM, diagonal-paired m-tiles (y and M/TM-1-y)
template<int OUT_MODE, int CAUSAL, int TM, int TN>
__device__ __forceinline__
void gemm_body(const f16* __restrict__ A, const f16* __restrict__ B,
               const float* __restrict__ bias, const float* __restrict__ bias2,
               void* __restrict__ Cv, void* __restrict__ C2,
               int M, int N, int K,
               long long sAb, long long sBb, long long sCb, float scale,
               int bx, int by, int bzi)
{
    constexpr int IM = TM / 32;
    constexpr int JN = TN / 32;

    int mtile, n0;
    if (CAUSAL == 1) {
        int rem = bx, mi = 0;
        while (rem > mi) { rem -= mi + 1; ++mi; }   // row mi has mi+1 n-blocks
        mtile = mi;
        n0 = rem * TN;
    } else {
        mtile = by;
        n0 = bx * TN;
    }

    const int tid  = threadIdx.x;
    const int wave = tid >> 6;
    const int lane = tid & 63;
    const long long bz = bzi;
    A += bz * sAb;
    B += bz * sBb;

    __shared__ f16 As[TM * BK];
    __shared__ f16 Bs[TN * BK];

    const int srow  = lane >> 2;                              // staging row in group
    const int scolS = (((lane & 3) ^ ((srow >> 1) & 3))) * 8; // swizzled chunk
    const int fr    = lane & 15;                              // frag row in 16-tile
    const int fkS   = (((lane >> 4) ^ ((fr >> 1) & 3))) * 8;  // swizzled frag chunk

    const int wm = (wave >> 1) * (TM / 2);
    const int wn = (wave & 1) * (TN / 2);

    const int npass = (CAUSAL == 2) ? 2 : 1;
    for (int pass = 0; pass < npass; ++pass) {
        const int mt = (CAUSAL == 2 && pass == 1) ? (M / TM - 1 - mtile) : mtile;
        const int m0 = mt * TM;
        const int Kend = (CAUSAL == 2) ? (m0 + TM) : K;

        f32x4 acc[IM][JN] = {};

        for (int k0 = 0; k0 < Kend; k0 += BK) {
            #pragma unroll
            for (int gg = 0; gg < TM / 64; ++gg) {
                const int g = wave * (TM / 64) + gg;
                gload_lds16(A + (long long)(m0 + g * 16 + srow) * K + (k0 + scolS),
                            &As[g * 512]);
            }
            #pragma unroll
            for (int gg = 0; gg < TN / 64; ++gg) {
                const int g = wave * (TN / 64) + gg;
                gload_lds16(B + (long long)(n0 + g * 16 + srow) * K + (k0 + scolS),
                            &Bs[g * 512]);
            }
            __syncthreads();

            f16x8 af[IM], bf[JN];
            #pragma unroll
            for (int i = 0; i < IM; ++i)
                af[i] = *(const f16x8*)&As[(wm + i * 16 + fr) * BK + fkS];
            #pragma unroll
            for (int j = 0; j < JN; ++j)
                bf[j] = *(const f16x8*)&Bs[(wn + j * 16 + fr) * BK + fkS];

            #pragma unroll
            for (int i = 0; i < IM; ++i)
                #pragma unroll
                for (int j = 0; j < JN; ++j)
                    acc[i][j] = __builtin_amdgcn_mfma_f32_16x16x32_f16(af[i], bf[j], acc[i][j], 0, 0, 0);
            __syncthreads();
        }

        // Epilogue. C/D layout: col = lane&15, row = (lane>>4)*4 + reg  [m89/m91]
        const int cn = lane & 15;
        const int cm = (lane >> 4) * 4;
        #pragma unroll
        for (int j = 0; j < JN; ++j) {
            const int gn = n0 + wn + j * 16 + cn;
            #pragma unroll
            for (int i = 0; i < IM; ++i) {
                const int gm = m0 + wm + i * 16 + cm;
                if (OUT_MODE == 0) {
                    const float bv = bias ? bias[gn] : 0.f;
                    float* C = (float*)Cv + bz * sCb;
                    #pragma unroll
                    for (int r = 0; r < 4; ++r)
                        C[(long long)(gm + r) * N + gn] = acc[i][j][r] * scale + bv;
                } else if (OUT_MODE == 1) {
                    const float bv = bias ? bias[(long long)bz * N + gn] : 0.f;
                    f16* C = (f16*)Cv + bz * sCb;
                    #pragma unroll
                    for (int r = 0; r < 4; ++r)
                        C[(long long)(gm + r) * N + gn] = (f16)(acc[i][j][r] * scale + bv);
                } else {  // OUT_MODE == 3: fused Qh/Vo projection (TM=TN=128)
                    const int sel = gn >> 10;
                    const int nn  = gn & 1023;
                    if (sel == 0) {          // Qh flat f16 [M,1024]
                        f16* C = (f16*)Cv;
                        #pragma unroll
                        for (int r = 0; r < 4; ++r)
                            C[(long long)(gm + r) * 1024 + nn] = (f16)acc[i][j][r];
                    } else {                 // Vo^T f16 [B][1024][2048] + bvo
                        const float bb = bias2[nn];
                        f16* C = (f16*)C2;
                        const int b = gm >> 11, s = gm & 2047;
                        f16x4 pk;
                        #pragma unroll
                        for (int r = 0; r < 4; ++r)
                            pk[r] = (f16)(acc[i][j][r] + bb);
                        *(f16x4*)&C[(long long)b * 2097152 + (long long)nn * 2048 + s] = pk;
                    }
                }
            }
        }
        if (CAUSAL == 2) __syncthreads();  // LDS reuse across passes
    }
}

template<int OUT_MODE, int CAUSAL, int TM, int TN>
__global__ __launch_bounds__(256, 2)
void gemm_bt(const f16* __restrict__ A, const f16* __restrict__ B,
             const float* __restrict__ bias, const float* __restrict__ bias2,
             void* __restrict__ Cv, void* __restrict__ C2,
             int M, int N, int K,
             long long sAb, long long sBb, long long sCb, float scale)
{
    gemm_body<OUT_MODE, CAUSAL, TM, TN>(A, B, bias, bias2, Cv, C2, M, N, K,
                                        sAb, sBb, sCb, scale,
                                        blockIdx.x, blockIdx.y, blockIdx.z);
}

// ================= R9: 256x256 8-phase projection GEMM =================
// Port of the verified 8-phase schedule (guide §5 template, m194-m201):
// BM=BN=256, BK=64, 512 threads (8 waves = 2M x 4N), LDS 128KiB dbuf.
// Per K-tile: 4 phases, each = {ds_read quadrant (+all B at p0) || issue one
// half-tile global_load_lds} -> s_barrier -> lgkmcnt(0) -> setprio(1) ->
// 16 MFMA -> setprio(0) -> [p3: counted vmcnt(4)] -> s_barrier.
// Staging into barrier-dead half-tiles: A(t+1) during t (p0/p1), B(t+2)
// during t (p2/p3, B region dead after p0). vmcnt never drains to 0 mid-loop.
// LDS swizzle: 16B slot ^= (row&7), both-sides (inverse-swizzled global src).

__device__ __forceinline__
void stage_half(const f16* __restrict__ G, int ldg, f16* lds_half,
                int grow0, int k0, int tid)
{
    // one 128-row x 64-col half-tile = 2 x (512 lanes x 16B)
    const int lr  = tid >> 3;                               // local row 0..63
    const int csw = ((tid & 7) * 8) ^ ((lr & 7) << 3);      // inverse-swizzled col
    gload_lds16(G + (long long)(grow0 + lr) * ldg + (k0 + csw),
                lds_half + ((tid >> 6) << 9));
    gload_lds16(G + (long long)(grow0 + 64 + lr) * ldg + (k0 + csw),
                lds_half + 4096 + ((tid >> 6) << 9));
}

__global__ __launch_bounds__(512, 2)
void gemm_proj_8ph(const f16* __restrict__ A, const f16* __restrict__ B,
                   const float* __restrict__ bvo,
                   f16* __restrict__ Qh, f16* __restrict__ Vt,
                   int M, int N, int K)
{
    (void)M;
    __shared__ f16 As[2][16384];   // [buf][256 rows][64 cols]
    __shared__ f16 Bs[2][16384];

    // XCD-chunked bijective swizzle (nwg % 8 == 0): XCD x -> 32 contiguous tiles
    const int nwg  = gridDim.x;
    const int orig = blockIdx.x;
    const int swz  = (orig & 7) * (nwg >> 3) + (orig >> 3);
    const int ntn  = N >> 8;
    const int mt = swz / ntn, nt = swz - mt * ntn;
    const int m0 = mt << 8, n0 = nt << 8;

    const int tid  = threadIdx.x;
    const int lane = tid & 63;
    const int wave = tid >> 6;
    const int wm = (wave >> 2) << 7;    // 0 / 128
    const int wn = (wave & 3) << 6;     // 0..192
    const int fr  = lane & 15;
    const int hk  = lane >> 4;          // 16B slot within K=32
    const int lsw = lane & 7;           // swizzle operand (== row&7 for frag rows)
    const int nkt = K >> 6;

    f32x4 acc[8][4] = {};
    f16x8 bf[4][2];

    // ---- prologue: stage A(0),B(0) then B(1); leave B(1)'s 4 loads in flight
    stage_half(A, K, &As[0][0],    m0,       0, tid);
    stage_half(A, K, &As[0][8192], m0 + 128, 0, tid);
    stage_half(B, K, &Bs[0][0],    n0,       0, tid);
    stage_half(B, K, &Bs[0][8192], n0 + 128, 0, tid);
    if (nkt > 1) {
        stage_half(B, K, &Bs[1][0],    n0,       64, tid);
        stage_half(B, K, &Bs[1][8192], n0 + 128, 64, tid);
        asm volatile("s_waitcnt vmcnt(4)" ::: "memory");
    } else {
        asm volatile("s_waitcnt vmcnt(0)" ::: "memory");
    }
    __builtin_amdgcn_s_barrier();

    for (int t = 0; t < nkt; ++t) {
        const f16* Ab = As[t & 1];
        const f16* Bb = Bs[t & 1];
        #pragma unroll
        for (int p = 0; p < 4; ++p) {
            // ds-read register subtile (phase p: A rows 2p,2p+1; p0 also all B)
            if (p == 0) {
                #pragma unroll
                for (int j = 0; j < 4; ++j)
                    #pragma unroll
                    for (int kk = 0; kk < 2; ++kk)
                        bf[j][kk] = *(const f16x8*)((const char*)Bb +
                            ((wn + j * 16 + fr) << 7) +
                            ((((kk << 2) | hk) ^ lsw) << 4));
            }
            f16x8 af[2][2];
            #pragma unroll
            for (int ii = 0; ii < 2; ++ii)
                #pragma unroll
                for (int kk = 0; kk < 2; ++kk)
                    af[ii][kk] = *(const f16x8*)((const char*)Ab +
                        ((wm + (2 * p + ii) * 16 + fr) << 7) +
                        ((((kk << 2) | hk) ^ lsw) << 4));

            // stage one half-tile into a dead region
            if (p == 0 && t + 1 < nkt)
                stage_half(A, K, &As[(t + 1) & 1][0],    m0,       (t + 1) << 6, tid);
            if (p == 1 && t + 1 < nkt)
                stage_half(A, K, &As[(t + 1) & 1][8192], m0 + 128, (t + 1) << 6, tid);
            if (p == 2 && t + 2 < nkt)
                stage_half(B, K, &Bs[t & 1][0],          n0,       (t + 2) << 6, tid);
            if (p == 3 && t + 2 < nkt)
                stage_half(B, K, &Bs[t & 1][8192],       n0 + 128, (t + 2) << 6, tid);

            if (p == 0) asm volatile("s_waitcnt lgkmcnt(8)" ::: "memory");
            __builtin_amdgcn_s_barrier();
            asm volatile("s_waitcnt lgkmcnt(0)" ::: "memory");
            __builtin_amdgcn_s_setprio(1);
            #pragma unroll
            for (int ii = 0; ii < 2; ++ii)
                #pragma unroll
                for (int j = 0; j < 4; ++j)
                    #pragma unroll
                    for (int kk = 0; kk < 2; ++kk)
                        acc[2 * p + ii][j] = __builtin_amdgcn_mfma_f32_16x16x32_f16(
                            af[ii][kk], bf[j][kk], acc[2 * p + ii][j], 0, 0, 0);
            __builtin_amdgcn_s_setprio(0);
            if (p == 3) {
                if (t + 2 < nkt) asm volatile("s_waitcnt vmcnt(4)" ::: "memory");
                else             asm volatile("s_waitcnt vmcnt(0)" ::: "memory");
            }
            __builtin_amdgcn_s_barrier();
        }
    }

    // ---- epilogue: Qh (n<1024) flat f16 [M,1024]; else Vt [B][1024][2048]+bvo
    const int cn  = lane & 15;
    const int cm4 = (lane >> 4) * 4;
    #pragma unroll
    for (int j = 0; j < 4; ++j) {
        const int gn  = n0 + wn + j * 16 + cn;
        const int sel = gn >> 10;        // uniform per block (n0 multiple of 256)
        const int nn  = gn & 1023;
        #pragma unroll
        for (int i = 0; i < 8; ++i) {
            const int gm = m0 + wm + i * 16 + cm4;
            if (sel == 0) {
                #pragma unroll
                for (int r = 0; r < 4; ++r)
                    Qh[(long long)(gm + r) * 1024 + nn] = (f16)acc[i][j][r];
            } else {
                const float bb = bvo[nn];
                const int b = gm >> 11, s = gm & 2047;
                f16x4 pk;
                #pragma unroll
                for (int r = 0; r < 4; ++r)
                    pk[r] = (f16)(acc[i][j][r] + bb);
                *(f16x4*)&Vt[(long long)b * 2097152 + (long long)nn * 2048 + s] = pk;
            }
        }
    }
}

// ---- prep: all input-only transforms in ONE launch ----
// regions (flat blockIdx.x): [0,8192) x-cast; [+1024) Wq cast; [+1024) Wk cast;
// [+1024) Wv cast; [+1024) Wo transpose; [+16) bvo; [+256) wv = Wk.bq/8
__global__ __launch_bounds__(256)
void prep(const float* __restrict__ x,  const float* __restrict__ Wq,
          const float* __restrict__ bq, const float* __restrict__ Wk,
          const float* __restrict__ Wv, const float* __restrict__ bv,
          const float* __restrict__ Wo,
          f16* __restrict__ xb,  f16* __restrict__ Wqf, f16* __restrict__ Wkf,
          f16* __restrict__ Wvf, f16* __restrict__ Wot,
          float* __restrict__ bvo, float* __restrict__ wvec)
{
    __shared__ f16 tile[32][33];
    __shared__ float red[4][64];
    const int t = threadIdx.x;
    int id = blockIdx.x;

    if (id < 8192) {                       // cast x -> xb (f16)
        const int i = (id * 256 + t) * 4;
        const float4 v = *(const float4*)&x[i];
        f16x4 o; o[0]=(f16)v.x; o[1]=(f16)v.y; o[2]=(f16)v.z; o[3]=(f16)v.w;
        *(f16x4*)&xb[i] = o;
        return;
    }
    id -= 8192;
    if (id < 3072) {                       // cast Wq/Wk/Wv (f16)
        const float* src = (id < 1024) ? Wq : (id < 2048) ? Wk : Wv;
        f16* dst = (id < 1024) ? Wqf : (id < 2048) ? Wkf : Wvf;
        const int i = ((id & 1023) * 256 + t) * 4;
        const float4 v = *(const float4*)&src[i];
        f16x4 o; o[0]=(f16)v.x; o[1]=(f16)v.y; o[2]=(f16)v.z; o[3]=(f16)v.w;
        *(f16x4*)&dst[i] = o;
        return;
    }
    id -= 3072;
    if (id < 1024) {                       // Wot[e][k] = (f16) Wo[k][e]
        const int bx = (id & 31) * 32, by = (id >> 5) * 32;
        const int tx = t & 31, ty = t >> 5;
        #pragma unroll
        for (int i = 0; i < 32; i += 8)
            tile[ty + i][tx] = (f16)Wo[(long long)(by + ty + i) * 1024 + (bx + tx)];
        __syncthreads();
        #pragma unroll
        for (int i = 0; i < 32; i += 8)
            Wot[(long long)(bx + ty + i) * 1024 + (by + tx)] = tile[tx][ty + i];
        return;
    }
    id -= 1024;
    if (id < 16) {                         // bvo[e] = sum_k bv[k] Wo[k][e]
        const int e0 = id * 64;
        const int wave = t >> 6, lane = t & 63;
        float acc = 0.f;
        for (int i = 0; i < 256; ++i) {
            const int k = wave * 256 + i;
            acc += bv[k] * Wo[(long long)k * 1024 + e0 + lane];
        }
        red[wave][lane] = acc;
        __syncthreads();
        if (wave == 0)
            bvo[e0 + lane] = red[0][lane] + red[1][lane] + red[2][lane] + red[3][lane];
        return;
    }
    id -= 16;
    {                                      // wvec[d] = (Wk[d,:].bq)/8
        const int row = id * 4 + (t >> 6);
        const int lane = t & 63;
        const float* src = Wk + (long long)row * 1024;
        float a = 0.f;
        #pragma unroll
        for (int tt = 0; tt < 16; ++tt) a += src[lane + 64 * tt] * bq[lane + 64 * tt];
        #pragma unroll
        for (int o = 32; o > 0; o >>= 1) a += __shfl_down(a, o);
        if (lane == 0) wvec[row] = a * 0.125f;
    }
}

// ---- dual: both weight-product GEMMs + cvec in ONE launch ----
// grid (16,16,3): z=0 -> WqkT = Wkf.Wqf^T; z=1 -> WvoT = Wot.Wvf^T;
// z=2 -> cbias[r] = xb[r,:].wvec.  z=2 coverage: 256 blocks x 4 waves x
// 8 rows = ALL 8192 rows (R8 BUG: x2 rows covered only batch 0 -> poisoned
// cbias for batches 1-3, absmax 5.5e-2).
__global__ __launch_bounds__(256, 2)
void dual_weights_cvec(const f16* __restrict__ Wkf, const f16* __restrict__ Wqf,
                       const f16* __restrict__ Wot, const f16* __restrict__ Wvf,
                       f16* __restrict__ Wcat2,
                       const f16* __restrict__ xb, const float* __restrict__ wvec,
                       float* __restrict__ cbias)
{
    if (blockIdx.z == 2) {
        const int flat = blockIdx.y * 16 + blockIdx.x;
        const int wave = threadIdx.x >> 6, lane = threadIdx.x & 63;
        #pragma unroll
        for (int rr = 0; rr < 8; ++rr) {
            const int row = (flat * 4 + wave) * 8 + rr;   // covers 0..8191
            const f16* src = xb + (long long)row * 1024;
            float a = 0.f;
            #pragma unroll
            for (int tt = 0; tt < 16; ++tt)
                a += (float)src[lane + 64 * tt] * wvec[lane + 64 * tt];
            #pragma unroll
            for (int o = 32; o > 0; o >>= 1) a += __shfl_down(a, o);
            if (lane == 0) cbias[row] = a;
        }
        return;
    }
    const f16* Ax = (blockIdx.z == 0) ? Wkf : Wot;
    const f16* Bx = (blockIdx.z == 0) ? Wqf : Wvf;
    f16* Cx = Wcat2 + (long long)blockIdx.z * 1024 * 1024;
    gemm_body<1, 0, 64, 64>(Ax, Bx, nullptr, nullptr, Cx, nullptr,
                            1024, 1024, 1024, 0, 0, 0, 1.f,
                            blockIdx.x, blockIdx.y, 0);
}

// One block per score row (b,q). Predicated 16B loads skip masked chunks.
__global__ __launch_bounds__(256)
void softmax_causal(const f16* __restrict__ Sc, f16* __restrict__ P, int S)
{
    const long long row = blockIdx.x;
    const int q = (int)(row % S);
    const f16* src = Sc + row * S;
    f16* dst = P + row * S;
    const int t = threadIdx.x;
    __shared__ float redm[4], reds[4];

    f16x8 vv = {};
    if (t * 8 <= q) vv = *(const f16x8*)&src[t * 8];
    float v[8];
    float mx = -3.0e38f;
    #pragma unroll
    for (int i = 0; i < 8; ++i) {
        const int k = t * 8 + i;
        v[i] = (float)vv[i];
        if (k <= q) mx = fmaxf(mx, v[i]);
    }
    #pragma unroll
    for (int o = 32; o > 0; o >>= 1) mx = fmaxf(mx, __shfl_down(mx, o));
    if ((t & 63) == 0) redm[t >> 6] = mx;
    __syncthreads();
    mx = fmaxf(fmaxf(redm[0], redm[1]), fmaxf(redm[2], redm[3]));

    float sum = 0.f;
    #pragma unroll
    for (int i = 0; i < 8; ++i) {
        const int k = t * 8 + i;
        v[i] = (k <= q) ? __expf(v[i] - mx) : 0.f;
        sum += v[i];
    }
    #pragma unroll
    for (int o = 32; o > 0; o >>= 1) sum += __shfl_down(sum, o);
    if ((t & 63) == 0) reds[t >> 6] = sum;
    __syncthreads();
    sum = reds[0] + reds[1] + reds[2] + reds[3];
    const float inv = 1.f / sum;
    f16x8 ov;
    #pragma unroll
    for (int i = 0; i < 8; ++i) ov[i] = (f16)(v[i] * inv);
    *(f16x8*)&dst[t * 8] = ov;
}

extern "C" void kernel_launch(void* const* d_in, const int* in_sizes, int n_in,
                              void* d_out, int out_size, void* d_ws, size_t ws_size,
                              hipStream_t stream)
{
    const float* x  = (const float*)d_in[0];
    const float* Wq = (const float*)d_in[1];
    const float* bq = (const float*)d_in[2];
    const float* Wk = (const float*)d_in[3];
    // bk (d_in[4]) unused: Q.bk^T is row-constant -> softmax-invariant.
    const float* Wv = (const float*)d_in[5];
    const float* bv = (const float*)d_in[6];
    const float* Wo = (const float*)d_in[7];
    const float* bo = (const float*)d_in[8];
    float* out = (float*)d_out;

    const int B = 4, S = 2048, D = 1024;
    const long long SD  = (long long)S * D;
    const long long SS  = (long long)S * S;
    const long long BSD = (long long)B * SD;
    const int MS = B * S;

    char* p = (char*)d_ws;
    f16*   xb    = (f16*)p;  p += BSD * 2;
    f16*   Wqf   = (f16*)p;  p += (long long)D * D * 2;
    f16*   Wkf   = (f16*)p;  p += (long long)D * D * 2;
    f16*   Wvf   = (f16*)p;  p += (long long)D * D * 2;
    f16*   Wot   = (f16*)p;  p += (long long)D * D * 2;
    f16*   Wcat2 = (f16*)p;  p += 2LL * D * D * 2;        // [WqkT; WvoT]
    float* bvo   = (float*)p; p += D * 4;
    float* wvec  = (float*)p; p += D * 4;
    float* cbias = (float*)p; p += (long long)MS * 4;
    f16*   Qh    = (f16*)p;  p += BSD * 2;
    f16*   Vt    = (f16*)p;  p += BSD * 2;                // Vo^T [B][1024][2048]
    f16*   Sc    = (f16*)p;  p += (long long)B * SS * 2;
    f16*   Pb    = (f16*)p;  p += (long long)B * SS * 2;

    dim3 blk(256);

    // 1) prep: all casts/transposes/small reductions, one launch (12560 blocks)
    prep<<<dim3(12560), blk, 0, stream>>>(x, Wq, bq, Wk, Wv, bv, Wo,
                                          xb, Wqf, Wkf, Wvf, Wot, bvo, wvec);

    // 2) weight-product GEMMs + cvec, one launch
    dual_weights_cvec<<<dim3(16, 16, 3), blk, 0, stream>>>(Wkf, Wqf, Wot, Wvf,
                                                           Wcat2, xb, wvec, cbias);

    // 3) fused projection: x @ [WqkT; WvoT]^T -> Qh flat; Vo^T batched (+bvo)
    //    R9: 256x256 8-phase counted-vmcnt kernel; 256 blocks = 1/CU.
    dim3 gproj((MS / 256) * (2 * D / 256));
    gemm_proj_8ph<<<gproj, dim3(512), 0, stream>>>(xb, Wcat2, bvo, Qh, Vt,
                                                   MS, 2 * D, D);

    // 4) scores = (Qh x^T)/8 + cbias[k], triangular blocks, f16 out
    dim3 gsc(136, 1, B);
    gemm_bt<1, 1, 128, 128><<<gsc, blk, 0, stream>>>(Qh, xb, cbias, nullptr,
                                                     Sc, nullptr,
                                                     S, S, D, SD, SD, SS, 0.125f);

    // 5) causal softmax -> P (f16), predicated loads
    softmax_causal<<<dim3((unsigned)(B * S)), blk, 0, stream>>>(Sc, Pb, S);

    // 6) out = P @ Vo + bo (fp32 final), diagonal-paired, 512 blocks
    dim3 gpv(D / 64, S / 128 / 2, B);
    gemm_bt<0, 2, 128, 64><<<gpv, blk, 0, stream>>>(Pb, Vt, bo, nullptr,
                                                    out, nullptr,
                                                    S, D, S, SS, SD, SD, 1.f);
}